// Round 1
// baseline (1551.235 us; speedup 1.0000x reference)
//
#include <hip/hip_runtime.h>

#define N_NODES 100000
#define N_EDGES 1600000
#define N_GRAPHS 1024
#define F_IN 128
#define HDIM 64

// ---------------------------------------------------------------------------
// zero deg + graph accumulators (ws is poisoned 0xAA before every launch)
__global__ void zero_k(float* __restrict__ deg, float* __restrict__ gsum,
                       float* __restrict__ gcnt) {
    int i = blockIdx.x * blockDim.x + threadIdx.x;
    int stride = gridDim.x * blockDim.x;
    for (int j = i; j < N_NODES; j += stride) deg[j] = 0.0f;
    for (int j = i; j < N_GRAPHS; j += stride) { gsum[j] = 0.0f; gcnt[j] = 0.0f; }
}

// deg[dst] += 1 for every real edge (self-loop handled as +1 in dinv_k)
__global__ void deg_k(const int* __restrict__ dst, float* __restrict__ deg) {
    int i = blockIdx.x * blockDim.x + threadIdx.x;
    int stride = gridDim.x * blockDim.x;
    for (int e = i; e < N_EDGES; e += stride)
        atomicAdd(&deg[dst[e]], 1.0f);
}

__global__ void dinv_k(float* __restrict__ deg) {
    int i = blockIdx.x * blockDim.x + threadIdx.x;
    if (i < N_NODES) deg[i] = 1.0f / sqrtf(deg[i] + 1.0f);  // +1 = self loop
}

// ---------------------------------------------------------------------------
// out[row][col] = sum_k reluOpt(A[row][k]) * W[k][col];  W staged in LDS.
// 3125 blocks x 32 rows = 100000 exactly. One wave handles one row at a time
// (A loads are wave-uniform broadcasts; Wl reads are 2-way bank alias = free).
template <int K, bool RELU_IN>
__global__ __launch_bounds__(256) void gemm_k(const float* __restrict__ A,
                                              const float* __restrict__ W,
                                              float* __restrict__ out) {
    __shared__ float Wl[K * 64];
    for (int i = threadIdx.x; i < K * 64; i += 256) Wl[i] = W[i];
    __syncthreads();
    const int col  = threadIdx.x & 63;
    const int rloc = threadIdx.x >> 6;  // wave id in block, 0..3
    const int ROWS = 32;
    int row0 = blockIdx.x * ROWS;
    for (int r = rloc; r < ROWS; r += 4) {
        int row = row0 + r;
        if (row >= N_NODES) return;
        const float* a = A + (size_t)row * K;
        float acc = 0.0f;
#pragma unroll
        for (int k = 0; k < K; ++k) {
            float av = a[k];
            if (RELU_IN) av = fmaxf(av, 0.0f);
            acc = fmaf(av, Wl[k * 64 + col], acc);
        }
        out[(size_t)row * HDIM + col] = acc;
    }
}

// h[i][c] = b[c] + hw[i][c] * dinv[i]^2   (bias + self-loop message)
__global__ void selfinit_k(float* __restrict__ h, const float* __restrict__ hw,
                           const float* __restrict__ b, const float* __restrict__ dinv) {
    int idx = blockIdx.x * blockDim.x + threadIdx.x;
    int stride = gridDim.x * blockDim.x;
    for (int j = idx; j < N_NODES * HDIM; j += stride) {
        int i = j >> 6, c = j & 63;
        float dv = dinv[i];
        h[j] = b[c] + hw[j] * dv * dv;
    }
}

// one wave per edge: lane = channel. Coalesced 256B gather + 64 f32 atomics.
__global__ __launch_bounds__(256) void scatter_k(const int* __restrict__ src,
                                                 const int* __restrict__ dst,
                                                 const float* __restrict__ dinv,
                                                 const float* __restrict__ hw,
                                                 float* __restrict__ h) {
    const int lane = threadIdx.x & 63;
    int wid = (blockIdx.x * 256 + threadIdx.x) >> 6;
    int wstride = gridDim.x * 4;
    for (int e = wid; e < N_EDGES; e += wstride) {
        int s = src[e], d = dst[e];
        float norm = dinv[s] * dinv[d];
        float v = hw[(size_t)s * HDIM + lane] * norm;
        atomicAdd(&h[(size_t)d * HDIM + lane], v);
    }
}

// per-node dot(h3[i], lin_w) -> segmented per-graph sum. batch is sorted, so
// most waves are graph-uniform: wave-reduce then one atomic.
__global__ __launch_bounds__(256) void pool_k(const float* __restrict__ h,
                                              const int* __restrict__ batch,
                                              const float* __restrict__ lw,
                                              float* __restrict__ gsum,
                                              float* __restrict__ gcnt) {
    int i = blockIdx.x * blockDim.x + threadIdx.x;
    bool act = i < N_NODES;
    float dot = 0.0f;
    int g = -1;
    if (act) {
        g = batch[i];
        const float4* row = (const float4*)(h + (size_t)i * HDIM);
        const float4* w4  = (const float4*)lw;
#pragma unroll
        for (int q = 0; q < 16; ++q) {
            float4 v = row[q], w = w4[q];
            dot = fmaf(v.x, w.x, dot);
            dot = fmaf(v.y, w.y, dot);
            dot = fmaf(v.z, w.z, dot);
            dot = fmaf(v.w, w.w, dot);
        }
    }
    int g0 = __shfl(g, 0);
    bool uni = (__ballot(act && (g == g0)) == ~0ULL);
    if (uni) {
        for (int o = 32; o > 0; o >>= 1) dot += __shfl_down(dot, o);
        if ((threadIdx.x & 63) == 0) {
            atomicAdd(&gsum[g0], dot);
            atomicAdd(&gcnt[g0], 64.0f);
        }
    } else if (act) {
        atomicAdd(&gsum[g], dot);
        atomicAdd(&gcnt[g], 1.0f);
    }
}

__global__ void final_k(float* __restrict__ out, const float* __restrict__ gsum,
                        const float* __restrict__ gcnt, const float* __restrict__ lb) {
    int g = blockIdx.x * blockDim.x + threadIdx.x;
    if (g < N_GRAPHS) out[g] = gsum[g] / fmaxf(gcnt[g], 1.0f) + lb[0];
}

// ---------------------------------------------------------------------------
extern "C" void kernel_launch(void* const* d_in, const int* in_sizes, int n_in,
                              void* d_out, int out_size, void* d_ws, size_t ws_size,
                              hipStream_t stream) {
    const float* x     = (const float*)d_in[0];
    const int*   eidx  = (const int*)d_in[1];   // [2, E] int32
    // d_in[2] = edge_attr — unused by the reference
    const int*   batch = (const int*)d_in[3];
    const float* W1 = (const float*)d_in[4];
    const float* b1 = (const float*)d_in[5];
    const float* W2 = (const float*)d_in[6];
    const float* b2 = (const float*)d_in[7];
    const float* W3 = (const float*)d_in[8];
    const float* b3 = (const float*)d_in[9];
    const float* lin_w = (const float*)d_in[10];
    const float* lin_b = (const float*)d_in[11];
    float* out = (float*)d_out;

    const int* src = eidx;            // edge_index[0]
    const int* dst = eidx + N_EDGES;  // edge_index[1]

    float* ws   = (float*)d_ws;
    float* dinv = ws;                   // 100000 (deg, then dinv in place)
    float* bufA = ws + 100352;          // 6.4M floats
    float* bufB = bufA + 6400000;       // 6.4M floats
    float* gsum = bufB + 6400000;       // 1024
    float* gcnt = gsum + 1024;          // 1024
    // total: ~51.6 MB of ws

    zero_k<<<512, 256, 0, stream>>>(dinv, gsum, gcnt);
    deg_k<<<4096, 256, 0, stream>>>(dst, dinv);
    dinv_k<<<(N_NODES + 255) / 256, 256, 0, stream>>>(dinv);

    // layer 1: hw1 = x @ W1 ; h1 = b1 + selfloop + scatter
    gemm_k<F_IN, false><<<3125, 256, 0, stream>>>(x, W1, bufA);
    selfinit_k<<<8192, 256, 0, stream>>>(bufB, bufA, b1, dinv);
    scatter_k<<<N_EDGES / 4, 256, 0, stream>>>(src, dst, dinv, bufA, bufB);

    // layer 2 (relu folded into A-load)
    gemm_k<HDIM, true><<<3125, 256, 0, stream>>>(bufB, W2, bufA);
    selfinit_k<<<8192, 256, 0, stream>>>(bufB, bufA, b2, dinv);
    scatter_k<<<N_EDGES / 4, 256, 0, stream>>>(src, dst, dinv, bufA, bufB);

    // layer 3 (no relu after)
    gemm_k<HDIM, true><<<3125, 256, 0, stream>>>(bufB, W3, bufA);
    selfinit_k<<<8192, 256, 0, stream>>>(bufB, bufA, b3, dinv);
    scatter_k<<<N_EDGES / 4, 256, 0, stream>>>(src, dst, dinv, bufA, bufB);

    // pool + head
    pool_k<<<(N_NODES + 255) / 256, 256, 0, stream>>>(bufB, batch, lin_w, gsum, gcnt);
    final_k<<<(N_GRAPHS + 255) / 256, 256, 0, stream>>>(out, gsum, gcnt, lin_b);
}

// Round 2
// 829.937 us; speedup vs baseline: 1.8691x; 1.8691x over previous
//
#include <hip/hip_runtime.h>

#define N_NODES 100000
#define N_EDGES 1600000
#define N_GRAPHS 1024
#define F_IN 128
#define HDIM 64
#define NB_SCAN 391  // ceil(100000/256)

// ---------------------------------------------------------------------------
__global__ void zero_k(int* __restrict__ cnt, float* __restrict__ gsum,
                       float* __restrict__ gcnt) {
    int i = blockIdx.x * blockDim.x + threadIdx.x;
    int stride = gridDim.x * blockDim.x;
    for (int j = i; j < N_NODES; j += stride) cnt[j] = 0;
    for (int j = i; j < N_GRAPHS; j += stride) { gsum[j] = 0.0f; gcnt[j] = 0.0f; }
}

// in-degree histogram (int atomics; also serves as degree for dinv)
__global__ void hist_k(const int* __restrict__ dst, int* __restrict__ cnt) {
    int i = blockIdx.x * blockDim.x + threadIdx.x;
    int stride = gridDim.x * blockDim.x;
    for (int e = i; e < N_EDGES; e += stride) atomicAdd(&cnt[dst[e]], 1);
}

__global__ void dinv_k(const int* __restrict__ cnt, float* __restrict__ dinv) {
    int i = blockIdx.x * blockDim.x + threadIdx.x;
    if (i < N_NODES) dinv[i] = rsqrtf((float)cnt[i] + 1.0f);  // +1 self loop
}

// ---- 2-level exclusive scan of cnt -> rowptr --------------------------------
__global__ __launch_bounds__(256) void scan_block_k(const int* __restrict__ cnt,
                                                    int* __restrict__ bsum) {
    __shared__ int sm[256];
    int i = blockIdx.x * 256 + threadIdx.x;
    sm[threadIdx.x] = (i < N_NODES) ? cnt[i] : 0;
    __syncthreads();
    for (int o = 128; o > 0; o >>= 1) {
        if (threadIdx.x < o) sm[threadIdx.x] += sm[threadIdx.x + o];
        __syncthreads();
    }
    if (threadIdx.x == 0) bsum[blockIdx.x] = sm[0];
}

__global__ __launch_bounds__(512) void scan_top_k(const int* __restrict__ bsum,
                                                  int* __restrict__ boff) {
    __shared__ int sm[512];
    int t = threadIdx.x;
    sm[t] = (t < NB_SCAN) ? bsum[t] : 0;
    __syncthreads();
    for (int o = 1; o < 512; o <<= 1) {
        int v = (t >= o) ? sm[t - o] : 0;
        __syncthreads();
        sm[t] += v;
        __syncthreads();
    }
    if (t < NB_SCAN) boff[t] = (t == 0) ? 0 : sm[t - 1];
}

__global__ __launch_bounds__(256) void scan_write_k(const int* __restrict__ cnt,
                                                    const int* __restrict__ boff,
                                                    int* __restrict__ rowptr,
                                                    int* __restrict__ cursor) {
    __shared__ int sm[256];
    int i = blockIdx.x * 256 + threadIdx.x;
    int v = (i < N_NODES) ? cnt[i] : 0;
    sm[threadIdx.x] = v;
    __syncthreads();
    for (int o = 1; o < 256; o <<= 1) {
        int add = (threadIdx.x >= o) ? sm[threadIdx.x - o] : 0;
        __syncthreads();
        sm[threadIdx.x] += add;
        __syncthreads();
    }
    if (i < N_NODES) {
        int excl = boff[blockIdx.x] + sm[threadIdx.x] - v;
        rowptr[i] = excl;
        cursor[i] = excl;
        if (i == N_NODES - 1) rowptr[N_NODES] = excl + v;
    }
}

// scatter edges into dst-sorted order; precompute per-edge norm
__global__ void bucket_k(const int* __restrict__ src, const int* __restrict__ dst,
                         const float* __restrict__ dinv, int* __restrict__ cursor,
                         int* __restrict__ es, float* __restrict__ enorm) {
    int i = blockIdx.x * blockDim.x + threadIdx.x;
    int stride = gridDim.x * blockDim.x;
    for (int e = i; e < N_EDGES; e += stride) {
        int s = src[e], d = dst[e];
        int pos = atomicAdd(&cursor[d], 1);
        es[pos] = s;
        enorm[pos] = dinv[s] * dinv[d];
    }
}

// ---------------------------------------------------------------------------
// out[row][col] = sum_k reluOpt(A[row][k]) * W[k][col]; 4 rows/wave, W in LDS.
template <int K, bool RELU_IN>
__global__ __launch_bounds__(256) void gemm_k(const float* __restrict__ A,
                                              const float* __restrict__ W,
                                              float* __restrict__ out) {
    __shared__ float Wl[K * 64];
    for (int i = threadIdx.x; i < K * 64; i += 256) Wl[i] = W[i];
    __syncthreads();
    const int col = threadIdx.x & 63;
    const int wid = threadIdx.x >> 6;
    int row0 = blockIdx.x * 16 + wid * 4;  // 6250 blocks * 16 rows = 100000
    const float* a0 = A + (size_t)row0 * K;
    const float* a1 = a0 + K;
    const float* a2 = a1 + K;
    const float* a3 = a2 + K;
    float acc0 = 0, acc1 = 0, acc2 = 0, acc3 = 0;
#pragma unroll
    for (int k = 0; k < K; ++k) {
        float w = Wl[k * 64 + col];
        float v0 = a0[k], v1 = a1[k], v2 = a2[k], v3 = a3[k];
        if (RELU_IN) {
            v0 = fmaxf(v0, 0.0f); v1 = fmaxf(v1, 0.0f);
            v2 = fmaxf(v2, 0.0f); v3 = fmaxf(v3, 0.0f);
        }
        acc0 = fmaf(v0, w, acc0);
        acc1 = fmaf(v1, w, acc1);
        acc2 = fmaf(v2, w, acc2);
        acc3 = fmaf(v3, w, acc3);
    }
    float* o = out + (size_t)row0 * HDIM + col;
    o[0] = acc0; o[HDIM] = acc1; o[2 * HDIM] = acc2; o[3 * HDIM] = acc3;
}

// ---------------------------------------------------------------------------
// one wave per dst node: acc = b + selfloop; += norm_e * hw[src_e]; plain store.
__global__ __launch_bounds__(256) void agg_k(const int* __restrict__ rowptr,
                                             const int* __restrict__ es,
                                             const float* __restrict__ enorm,
                                             const float* __restrict__ dinv,
                                             const float* __restrict__ hw,
                                             const float* __restrict__ b,
                                             float* __restrict__ h) {
    const int lane = threadIdx.x & 63;
    int node = (blockIdx.x * 256 + threadIdx.x) >> 6;
    if (node >= N_NODES) return;
    int e0 = rowptr[node], e1 = rowptr[node + 1];
    float dv = dinv[node];
    float acc = b[lane] + hw[(size_t)node * HDIM + lane] * dv * dv;
    int e = e0;
    for (; e + 1 < e1; e += 2) {
        int s0 = es[e], s1 = es[e + 1];
        float n0 = enorm[e], n1 = enorm[e + 1];
        float v0 = hw[(size_t)s0 * HDIM + lane];
        float v1 = hw[(size_t)s1 * HDIM + lane];
        acc = fmaf(v0, n0, acc);
        acc = fmaf(v1, n1, acc);
    }
    if (e < e1) {
        int s = es[e];
        acc = fmaf(hw[(size_t)s * HDIM + lane], enorm[e], acc);
    }
    h[(size_t)node * HDIM + lane] = acc;
}

// ---------------------------------------------------------------------------
__global__ __launch_bounds__(256) void pool_k(const float* __restrict__ h,
                                              const int* __restrict__ batch,
                                              const float* __restrict__ lw,
                                              float* __restrict__ gsum,
                                              float* __restrict__ gcnt) {
    int i = blockIdx.x * blockDim.x + threadIdx.x;
    bool act = i < N_NODES;
    float dot = 0.0f;
    int g = -1;
    if (act) {
        g = batch[i];
        const float4* row = (const float4*)(h + (size_t)i * HDIM);
        const float4* w4  = (const float4*)lw;
#pragma unroll
        for (int q = 0; q < 16; ++q) {
            float4 v = row[q], w = w4[q];
            dot = fmaf(v.x, w.x, dot);
            dot = fmaf(v.y, w.y, dot);
            dot = fmaf(v.z, w.z, dot);
            dot = fmaf(v.w, w.w, dot);
        }
    }
    int g0 = __shfl(g, 0);
    bool uni = (__ballot(act && (g == g0)) == ~0ULL);
    if (uni) {
        for (int o = 32; o > 0; o >>= 1) dot += __shfl_down(dot, o);
        if ((threadIdx.x & 63) == 0) {
            atomicAdd(&gsum[g0], dot);
            atomicAdd(&gcnt[g0], 64.0f);
        }
    } else if (act) {
        atomicAdd(&gsum[g], dot);
        atomicAdd(&gcnt[g], 1.0f);
    }
}

__global__ void final_k(float* __restrict__ out, const float* __restrict__ gsum,
                        const float* __restrict__ gcnt, const float* __restrict__ lb) {
    int g = blockIdx.x * blockDim.x + threadIdx.x;
    if (g < N_GRAPHS) out[g] = gsum[g] / fmaxf(gcnt[g], 1.0f) + lb[0];
}

// ---------------------------------------------------------------------------
extern "C" void kernel_launch(void* const* d_in, const int* in_sizes, int n_in,
                              void* d_out, int out_size, void* d_ws, size_t ws_size,
                              hipStream_t stream) {
    const float* x     = (const float*)d_in[0];
    const int*   eidx  = (const int*)d_in[1];   // [2, E] int32
    const int*   batch = (const int*)d_in[3];
    const float* W1 = (const float*)d_in[4];
    const float* b1 = (const float*)d_in[5];
    const float* W2 = (const float*)d_in[6];
    const float* b2 = (const float*)d_in[7];
    const float* W3 = (const float*)d_in[8];
    const float* b3 = (const float*)d_in[9];
    const float* lin_w = (const float*)d_in[10];
    const float* lin_b = (const float*)d_in[11];
    float* out = (float*)d_out;

    const int* src = eidx;
    const int* dst = eidx + N_EDGES;

    float* ws     = (float*)d_ws;
    float* dinv   = ws;                         // 100352
    int*   cnt    = (int*)(ws + 100352);        // 100352
    int*   rowptr = cnt + 100352;               // 100352 (needs 100001)
    int*   cursor = rowptr + 100352;            // 100352
    int*   bsum   = cursor + 100352;            // 512
    int*   boff   = bsum + 512;                 // 512
    int*   es     = boff + 512;                 // 1600000
    float* enorm  = (float*)(es + 1600000);     // 1600000
    float* bufA   = enorm + 1600000;            // 6400000
    float* bufB   = bufA + 6400000;             // 6400000
    float* gsum   = bufB + 6400000;             // 1024
    float* gcnt   = gsum + 1024;                // 1024   (~66 MB total)

    // ---- CSR build (once; reused by all 3 layers) ----
    zero_k<<<512, 256, 0, stream>>>(cnt, gsum, gcnt);
    hist_k<<<4096, 256, 0, stream>>>(dst, cnt);
    dinv_k<<<(N_NODES + 255) / 256, 256, 0, stream>>>(cnt, dinv);
    scan_block_k<<<NB_SCAN, 256, 0, stream>>>(cnt, bsum);
    scan_top_k<<<1, 512, 0, stream>>>(bsum, boff);
    scan_write_k<<<NB_SCAN, 256, 0, stream>>>(cnt, boff, rowptr, cursor);
    bucket_k<<<4096, 256, 0, stream>>>(src, dst, dinv, cursor, es, enorm);

    // ---- 3 GCN layers ----
    gemm_k<F_IN, false><<<6250, 256, 0, stream>>>(x, W1, bufA);
    agg_k<<<25000, 256, 0, stream>>>(rowptr, es, enorm, dinv, bufA, b1, bufB);

    gemm_k<HDIM, true><<<6250, 256, 0, stream>>>(bufB, W2, bufA);
    agg_k<<<25000, 256, 0, stream>>>(rowptr, es, enorm, dinv, bufA, b2, bufB);

    gemm_k<HDIM, true><<<6250, 256, 0, stream>>>(bufB, W3, bufA);
    agg_k<<<25000, 256, 0, stream>>>(rowptr, es, enorm, dinv, bufA, b3, bufB);

    // ---- pool + head ----
    pool_k<<<(N_NODES + 255) / 256, 256, 0, stream>>>(bufB, batch, lin_w, gsum, gcnt);
    final_k<<<(N_GRAPHS + 255) / 256, 256, 0, stream>>>(out, gsum, gcnt, lin_b);
}

// Round 3
// 784.592 us; speedup vs baseline: 1.9771x; 1.0578x over previous
//
#include <hip/hip_runtime.h>

#define N_NODES 100000
#define N_EDGES 1600000
#define N_GRAPHS 1024
#define F_IN 128
#define HDIM 64
#define NB_SCAN 391  // ceil(100000/256)

// ---------------------------------------------------------------------------
__global__ void zero_k(int* __restrict__ cnt, float* __restrict__ gsum,
                       float* __restrict__ gcnt) {
    int i = blockIdx.x * blockDim.x + threadIdx.x;
    int stride = gridDim.x * blockDim.x;
    for (int j = i; j < N_NODES; j += stride) cnt[j] = 0;
    for (int j = i; j < N_GRAPHS; j += stride) { gsum[j] = 0.0f; gcnt[j] = 0.0f; }
}

__global__ void hist_k(const int* __restrict__ dst, int* __restrict__ cnt) {
    int i = blockIdx.x * blockDim.x + threadIdx.x;
    int stride = gridDim.x * blockDim.x;
    for (int e = i; e < N_EDGES; e += stride) atomicAdd(&cnt[dst[e]], 1);
}

__global__ void dinv_k(const int* __restrict__ cnt, float* __restrict__ dinv) {
    int i = blockIdx.x * blockDim.x + threadIdx.x;
    if (i < N_NODES) dinv[i] = rsqrtf((float)cnt[i] + 1.0f);  // +1 self loop
}

// ---- 2-level exclusive scan of cnt -> rowptr --------------------------------
__global__ __launch_bounds__(256) void scan_block_k(const int* __restrict__ cnt,
                                                    int* __restrict__ bsum) {
    __shared__ int sm[256];
    int i = blockIdx.x * 256 + threadIdx.x;
    sm[threadIdx.x] = (i < N_NODES) ? cnt[i] : 0;
    __syncthreads();
    for (int o = 128; o > 0; o >>= 1) {
        if (threadIdx.x < o) sm[threadIdx.x] += sm[threadIdx.x + o];
        __syncthreads();
    }
    if (threadIdx.x == 0) bsum[blockIdx.x] = sm[0];
}

__global__ __launch_bounds__(512) void scan_top_k(const int* __restrict__ bsum,
                                                  int* __restrict__ boff) {
    __shared__ int sm[512];
    int t = threadIdx.x;
    sm[t] = (t < NB_SCAN) ? bsum[t] : 0;
    __syncthreads();
    for (int o = 1; o < 512; o <<= 1) {
        int v = (t >= o) ? sm[t - o] : 0;
        __syncthreads();
        sm[t] += v;
        __syncthreads();
    }
    if (t < NB_SCAN) boff[t] = (t == 0) ? 0 : sm[t - 1];
}

__global__ __launch_bounds__(256) void scan_write_k(const int* __restrict__ cnt,
                                                    const int* __restrict__ boff,
                                                    int* __restrict__ rowptr,
                                                    int* __restrict__ cursor) {
    __shared__ int sm[256];
    int i = blockIdx.x * 256 + threadIdx.x;
    int v = (i < N_NODES) ? cnt[i] : 0;
    sm[threadIdx.x] = v;
    __syncthreads();
    for (int o = 1; o < 256; o <<= 1) {
        int add = (threadIdx.x >= o) ? sm[threadIdx.x - o] : 0;
        __syncthreads();
        sm[threadIdx.x] += add;
        __syncthreads();
    }
    if (i < N_NODES) {
        int excl = boff[blockIdx.x] + sm[threadIdx.x] - v;
        rowptr[i] = excl;
        cursor[i] = excl;
        if (i == N_NODES - 1) rowptr[N_NODES] = excl + v;
    }
}

// scatter edges into dst-sorted order; pack (src, norm) as int2
__global__ void bucket_k(const int* __restrict__ src, const int* __restrict__ dst,
                         const float* __restrict__ dinv, int* __restrict__ cursor,
                         int2* __restrict__ epack) {
    int i = blockIdx.x * blockDim.x + threadIdx.x;
    int stride = gridDim.x * blockDim.x;
    for (int e = i; e < N_EDGES; e += stride) {
        int s = src[e], d = dst[e];
        int pos = atomicAdd(&cursor[d], 1);
        epack[pos] = make_int2(s, __float_as_int(dinv[s] * dinv[d]));
    }
}

// ---------------------------------------------------------------------------
// Register-blocked GEMM, no LDS: out[row][col] = sum_k A[row][k] * W[k][col].
// 256 threads: tx = t&7 -> 8 cols each (64 cols), ty = t>>3 -> 4 rows each
// (128 rows/block). Wave-level same-address merging handles the 8-lane
// duplication of A (per ty) and W (per tx); W stays L2-resident.
#define FMA8(av, wl, wh, accrow)                       \
    accrow[0] = fmaf(av, wl.x, accrow[0]);             \
    accrow[1] = fmaf(av, wl.y, accrow[1]);             \
    accrow[2] = fmaf(av, wl.z, accrow[2]);             \
    accrow[3] = fmaf(av, wl.w, accrow[3]);             \
    accrow[4] = fmaf(av, wh.x, accrow[4]);             \
    accrow[5] = fmaf(av, wh.y, accrow[5]);             \
    accrow[6] = fmaf(av, wh.z, accrow[6]);             \
    accrow[7] = fmaf(av, wh.w, accrow[7]);

template <int K>
__global__ __launch_bounds__(256) void gemm_k(const float* __restrict__ A,
                                              const float* __restrict__ W,
                                              float* __restrict__ out) {
    const int tx = threadIdx.x & 7;
    const int ty = threadIdx.x >> 3;
    const int c0 = tx * 8;
    const int r0 = blockIdx.x * 128 + ty * 4;
    float acc[4][8];
#pragma unroll
    for (int i = 0; i < 4; ++i)
#pragma unroll
        for (int j = 0; j < 8; ++j) acc[i][j] = 0.0f;

#pragma unroll 2
    for (int kc = 0; kc < K; kc += 4) {
        float4 a[4];
#pragma unroll
        for (int i = 0; i < 4; ++i) {
            int r = r0 + i;
            a[i] = (r < N_NODES) ? *(const float4*)(A + (size_t)r * K + kc)
                                 : make_float4(0.f, 0.f, 0.f, 0.f);
        }
        float4 wlo[4], whi[4];
#pragma unroll
        for (int j = 0; j < 4; ++j) {
            wlo[j] = *(const float4*)(W + (size_t)(kc + j) * HDIM + c0);
            whi[j] = *(const float4*)(W + (size_t)(kc + j) * HDIM + c0 + 4);
        }
#pragma unroll
        for (int i = 0; i < 4; ++i) {
            FMA8(a[i].x, wlo[0], whi[0], acc[i]);
            FMA8(a[i].y, wlo[1], whi[1], acc[i]);
            FMA8(a[i].z, wlo[2], whi[2], acc[i]);
            FMA8(a[i].w, wlo[3], whi[3], acc[i]);
        }
    }
#pragma unroll
    for (int i = 0; i < 4; ++i) {
        int r = r0 + i;
        if (r < N_NODES) {
            float4 lo = make_float4(acc[i][0], acc[i][1], acc[i][2], acc[i][3]);
            float4 hi = make_float4(acc[i][4], acc[i][5], acc[i][6], acc[i][7]);
            *(float4*)(out + (size_t)r * HDIM + c0) = lo;
            *(float4*)(out + (size_t)r * HDIM + c0 + 4) = hi;
        }
    }
}

// ---------------------------------------------------------------------------
// one wave per dst node. Lane-cooperative metadata: 64 packed (src,norm) per
// coalesced load, shfl-broadcast, then one coalesced 256B gather per edge.
template <bool RELU_OUT>
__global__ __launch_bounds__(256) void agg_k(const int* __restrict__ rowptr,
                                             const int2* __restrict__ epack,
                                             const float* __restrict__ dinv,
                                             const float* __restrict__ hw,
                                             const float* __restrict__ b,
                                             float* __restrict__ h) {
    const int lane = threadIdx.x & 63;
    int node = (blockIdx.x * 256 + threadIdx.x) >> 6;
    if (node >= N_NODES) return;
    int e0 = rowptr[node], e1 = rowptr[node + 1];
    float dv = dinv[node];
    float acc = b[lane] + hw[(size_t)node * HDIM + lane] * dv * dv;
    for (int base = e0; base < e1; base += 64) {
        int n = min(64, e1 - base);
        int se = 0, ne = 0;
        if (base + lane < e1) {
            int2 m = epack[base + lane];
            se = m.x; ne = m.y;
        }
        for (int j = 0; j < n; ++j) {
            int sj = __shfl(se, j);
            float nj = __int_as_float(__shfl(ne, j));
            acc = fmaf(hw[(size_t)sj * HDIM + lane], nj, acc);
        }
    }
    if (RELU_OUT) acc = fmaxf(acc, 0.0f);
    h[(size_t)node * HDIM + lane] = acc;
}

// ---------------------------------------------------------------------------
__global__ __launch_bounds__(256) void pool_k(const float* __restrict__ h,
                                              const int* __restrict__ batch,
                                              const float* __restrict__ lw,
                                              float* __restrict__ gsum,
                                              float* __restrict__ gcnt) {
    int i = blockIdx.x * blockDim.x + threadIdx.x;
    bool act = i < N_NODES;
    float dot = 0.0f;
    int g = -1;
    if (act) {
        g = batch[i];
        const float4* row = (const float4*)(h + (size_t)i * HDIM);
        const float4* w4  = (const float4*)lw;
#pragma unroll
        for (int q = 0; q < 16; ++q) {
            float4 v = row[q], w = w4[q];
            dot = fmaf(v.x, w.x, dot);
            dot = fmaf(v.y, w.y, dot);
            dot = fmaf(v.z, w.z, dot);
            dot = fmaf(v.w, w.w, dot);
        }
    }
    int g0 = __shfl(g, 0);
    bool uni = (__ballot(act && (g == g0)) == ~0ULL);
    if (uni) {
        for (int o = 32; o > 0; o >>= 1) dot += __shfl_down(dot, o);
        if ((threadIdx.x & 63) == 0) {
            atomicAdd(&gsum[g0], dot);
            atomicAdd(&gcnt[g0], 64.0f);
        }
    } else if (act) {
        atomicAdd(&gsum[g], dot);
        atomicAdd(&gcnt[g], 1.0f);
    }
}

__global__ void final_k(float* __restrict__ out, const float* __restrict__ gsum,
                        const float* __restrict__ gcnt, const float* __restrict__ lb) {
    int g = blockIdx.x * blockDim.x + threadIdx.x;
    if (g < N_GRAPHS) out[g] = gsum[g] / fmaxf(gcnt[g], 1.0f) + lb[0];
}

// ---------------------------------------------------------------------------
extern "C" void kernel_launch(void* const* d_in, const int* in_sizes, int n_in,
                              void* d_out, int out_size, void* d_ws, size_t ws_size,
                              hipStream_t stream) {
    const float* x     = (const float*)d_in[0];
    const int*   eidx  = (const int*)d_in[1];   // [2, E] int32
    const int*   batch = (const int*)d_in[3];
    const float* W1 = (const float*)d_in[4];
    const float* b1 = (const float*)d_in[5];
    const float* W2 = (const float*)d_in[6];
    const float* b2 = (const float*)d_in[7];
    const float* W3 = (const float*)d_in[8];
    const float* b3 = (const float*)d_in[9];
    const float* lin_w = (const float*)d_in[10];
    const float* lin_b = (const float*)d_in[11];
    float* out = (float*)d_out;

    const int* src = eidx;
    const int* dst = eidx + N_EDGES;

    float* ws     = (float*)d_ws;
    float* dinv   = ws;                         // 100352
    int*   cnt    = (int*)(ws + 100352);        // 100352
    int*   rowptr = cnt + 100352;               // 100352 (needs 100001)
    int*   cursor = rowptr + 100352;            // 100352
    int*   bsum   = cursor + 100352;            // 512
    int*   boff   = bsum + 512;                 // 512
    int2*  epack  = (int2*)(boff + 512);        // 1.6M int2 (12.8 MB)
    float* bufA   = (float*)(epack + N_EDGES);  // 6.4M
    float* bufB   = bufA + 6400000;             // 6.4M
    float* gsum   = bufB + 6400000;             // 1024
    float* gcnt   = gsum + 1024;                // 1024   (~65 MB total)

    // ---- CSR build (once; reused by all 3 layers) ----
    zero_k<<<512, 256, 0, stream>>>(cnt, gsum, gcnt);
    hist_k<<<4096, 256, 0, stream>>>(dst, cnt);
    dinv_k<<<(N_NODES + 255) / 256, 256, 0, stream>>>(cnt, dinv);
    scan_block_k<<<NB_SCAN, 256, 0, stream>>>(cnt, bsum);
    scan_top_k<<<1, 512, 0, stream>>>(bsum, boff);
    scan_write_k<<<NB_SCAN, 256, 0, stream>>>(cnt, boff, rowptr, cursor);
    bucket_k<<<4096, 256, 0, stream>>>(src, dst, dinv, cursor, epack);

    // ---- 3 GCN layers (relu folded into agg store) ----
    gemm_k<F_IN><<<782, 256, 0, stream>>>(x, W1, bufA);
    agg_k<true><<<25000, 256, 0, stream>>>(rowptr, epack, dinv, bufA, b1, bufB);

    gemm_k<HDIM><<<782, 256, 0, stream>>>(bufB, W2, bufA);
    agg_k<true><<<25000, 256, 0, stream>>>(rowptr, epack, dinv, bufA, b2, bufB);

    gemm_k<HDIM><<<782, 256, 0, stream>>>(bufB, W3, bufA);
    agg_k<false><<<25000, 256, 0, stream>>>(rowptr, epack, dinv, bufA, b3, bufB);

    // ---- pool + head ----
    pool_k<<<(N_NODES + 255) / 256, 256, 0, stream>>>(bufB, batch, lin_w, gsum, gcnt);
    final_k<<<(N_GRAPHS + 255) / 256, 256, 0, stream>>>(out, gsum, gcnt, lin_b);
}

// Round 4
// 714.711 us; speedup vs baseline: 2.1704x; 1.0978x over previous
//
#include <hip/hip_runtime.h>

#define N_NODES 100000
#define N_EDGES 1600000
#define N_GRAPHS 1024
#define F_IN 128
#define HDIM 64
#define NB_SCAN 391  // ceil(100000/256)

// ---------------------------------------------------------------------------
__global__ void zero_k(int* __restrict__ cnt, float* __restrict__ gsum,
                       float* __restrict__ gcnt) {
    int i = blockIdx.x * blockDim.x + threadIdx.x;
    int stride = gridDim.x * blockDim.x;
    for (int j = i; j < N_NODES; j += stride) cnt[j] = 0;
    for (int j = i; j < N_GRAPHS; j += stride) { gsum[j] = 0.0f; gcnt[j] = 0.0f; }
}

__global__ void hist_k(const int* __restrict__ dst, int* __restrict__ cnt) {
    int i = blockIdx.x * blockDim.x + threadIdx.x;
    int stride = gridDim.x * blockDim.x;
    for (int e = i; e < N_EDGES; e += stride) atomicAdd(&cnt[dst[e]], 1);
}

__global__ void dinv_k(const int* __restrict__ cnt, float* __restrict__ dinv) {
    int i = blockIdx.x * blockDim.x + threadIdx.x;
    if (i < N_NODES) dinv[i] = rsqrtf((float)cnt[i] + 1.0f);  // +1 self loop
}

// ---- 2-level exclusive scan of cnt -> rowptr --------------------------------
__global__ __launch_bounds__(256) void scan_block_k(const int* __restrict__ cnt,
                                                    int* __restrict__ bsum) {
    __shared__ int sm[256];
    int i = blockIdx.x * 256 + threadIdx.x;
    sm[threadIdx.x] = (i < N_NODES) ? cnt[i] : 0;
    __syncthreads();
    for (int o = 128; o > 0; o >>= 1) {
        if (threadIdx.x < o) sm[threadIdx.x] += sm[threadIdx.x + o];
        __syncthreads();
    }
    if (threadIdx.x == 0) bsum[blockIdx.x] = sm[0];
}

__global__ __launch_bounds__(512) void scan_top_k(const int* __restrict__ bsum,
                                                  int* __restrict__ boff) {
    __shared__ int sm[512];
    int t = threadIdx.x;
    sm[t] = (t < NB_SCAN) ? bsum[t] : 0;
    __syncthreads();
    for (int o = 1; o < 512; o <<= 1) {
        int v = (t >= o) ? sm[t - o] : 0;
        __syncthreads();
        sm[t] += v;
        __syncthreads();
    }
    if (t < NB_SCAN) boff[t] = (t == 0) ? 0 : sm[t - 1];
}

__global__ __launch_bounds__(256) void scan_write_k(const int* __restrict__ cnt,
                                                    const int* __restrict__ boff,
                                                    int* __restrict__ rowptr,
                                                    int* __restrict__ cursor) {
    __shared__ int sm[256];
    int i = blockIdx.x * 256 + threadIdx.x;
    int v = (i < N_NODES) ? cnt[i] : 0;
    sm[threadIdx.x] = v;
    __syncthreads();
    for (int o = 1; o < 256; o <<= 1) {
        int add = (threadIdx.x >= o) ? sm[threadIdx.x - o] : 0;
        __syncthreads();
        sm[threadIdx.x] += add;
        __syncthreads();
    }
    if (i < N_NODES) {
        int excl = boff[blockIdx.x] + sm[threadIdx.x] - v;
        rowptr[i] = excl;
        cursor[i] = excl;
        if (i == N_NODES - 1) rowptr[N_NODES] = excl + v;
    }
}

// scatter edges into dst-sorted order; pack (src, norm) as int2
__global__ void bucket_k(const int* __restrict__ src, const int* __restrict__ dst,
                         const float* __restrict__ dinv, int* __restrict__ cursor,
                         int2* __restrict__ epack) {
    int i = blockIdx.x * blockDim.x + threadIdx.x;
    int stride = gridDim.x * blockDim.x;
    for (int e = i; e < N_EDGES; e += stride) {
        int s = src[e], d = dst[e];
        int pos = atomicAdd(&cursor[d], 1);
        epack[pos] = make_int2(s, __float_as_int(dinv[s] * dinv[d]));
    }
}

// ---------------------------------------------------------------------------
// Register-blocked GEMM, no LDS: out[row][col] = sum_k A[row][k] * W[k][col].
#define FMA8(av, wl, wh, accrow)                       \
    accrow[0] = fmaf(av, wl.x, accrow[0]);             \
    accrow[1] = fmaf(av, wl.y, accrow[1]);             \
    accrow[2] = fmaf(av, wl.z, accrow[2]);             \
    accrow[3] = fmaf(av, wl.w, accrow[3]);             \
    accrow[4] = fmaf(av, wh.x, accrow[4]);             \
    accrow[5] = fmaf(av, wh.y, accrow[5]);             \
    accrow[6] = fmaf(av, wh.z, accrow[6]);             \
    accrow[7] = fmaf(av, wh.w, accrow[7]);

template <int K>
__global__ __launch_bounds__(256) void gemm_k(const float* __restrict__ A,
                                              const float* __restrict__ W,
                                              float* __restrict__ out) {
    const int tx = threadIdx.x & 7;
    const int ty = threadIdx.x >> 3;
    const int c0 = tx * 8;
    const int r0 = blockIdx.x * 128 + ty * 4;
    float acc[4][8];
#pragma unroll
    for (int i = 0; i < 4; ++i)
#pragma unroll
        for (int j = 0; j < 8; ++j) acc[i][j] = 0.0f;

#pragma unroll 2
    for (int kc = 0; kc < K; kc += 4) {
        float4 a[4];
#pragma unroll
        for (int i = 0; i < 4; ++i) {
            int r = r0 + i;
            a[i] = (r < N_NODES) ? *(const float4*)(A + (size_t)r * K + kc)
                                 : make_float4(0.f, 0.f, 0.f, 0.f);
        }
        float4 wlo[4], whi[4];
#pragma unroll
        for (int j = 0; j < 4; ++j) {
            wlo[j] = *(const float4*)(W + (size_t)(kc + j) * HDIM + c0);
            whi[j] = *(const float4*)(W + (size_t)(kc + j) * HDIM + c0 + 4);
        }
#pragma unroll
        for (int i = 0; i < 4; ++i) {
            FMA8(a[i].x, wlo[0], whi[0], acc[i]);
            FMA8(a[i].y, wlo[1], whi[1], acc[i]);
            FMA8(a[i].z, wlo[2], whi[2], acc[i]);
            FMA8(a[i].w, wlo[3], whi[3], acc[i]);
        }
    }
#pragma unroll
    for (int i = 0; i < 4; ++i) {
        int r = r0 + i;
        if (r < N_NODES) {
            float4 lo = make_float4(acc[i][0], acc[i][1], acc[i][2], acc[i][3]);
            float4 hi = make_float4(acc[i][4], acc[i][5], acc[i][6], acc[i][7]);
            *(float4*)(out + (size_t)r * HDIM + c0) = lo;
            *(float4*)(out + (size_t)r * HDIM + c0 + 4) = hi;
        }
    }
}

// ---------------------------------------------------------------------------
// one wave per dst node. Edge metadata read as wave-uniform int4 broadcasts
// (consecutive waves stream consecutive epack ranges -> L1/L2 hits); 8 row
// gathers batched per iteration for memory-level parallelism.
template <bool RELU_OUT>
__global__ __launch_bounds__(256) void agg_k(const int* __restrict__ rowptr,
                                             const int2* __restrict__ epack,
                                             const float* __restrict__ dinv,
                                             const float* __restrict__ hw,
                                             const float* __restrict__ b,
                                             float* __restrict__ h) {
    const int lane = threadIdx.x & 63;
    int node = (blockIdx.x * 256 + threadIdx.x) >> 6;
    if (node >= N_NODES) return;
    int e0 = rowptr[node], e1 = rowptr[node + 1];
    float dv = dinv[node];
    float acc = b[lane] + hw[(size_t)node * HDIM + lane] * dv * dv;

    int e = e0;
    if ((e & 1) && e < e1) {  // align to 16B for int4 loads
        int2 m = epack[e];
        acc = fmaf(hw[(size_t)m.x * HDIM + lane], __int_as_float(m.y), acc);
        ++e;
    }
    for (; e + 8 <= e1; e += 8) {
        int4 m0 = *(const int4*)(epack + e);
        int4 m1 = *(const int4*)(epack + e + 2);
        int4 m2 = *(const int4*)(epack + e + 4);
        int4 m3 = *(const int4*)(epack + e + 6);
        float v0 = hw[(size_t)m0.x * HDIM + lane];
        float v1 = hw[(size_t)m0.z * HDIM + lane];
        float v2 = hw[(size_t)m1.x * HDIM + lane];
        float v3 = hw[(size_t)m1.z * HDIM + lane];
        float v4 = hw[(size_t)m2.x * HDIM + lane];
        float v5 = hw[(size_t)m2.z * HDIM + lane];
        float v6 = hw[(size_t)m3.x * HDIM + lane];
        float v7 = hw[(size_t)m3.z * HDIM + lane];
        acc = fmaf(v0, __int_as_float(m0.y), acc);
        acc = fmaf(v1, __int_as_float(m0.w), acc);
        acc = fmaf(v2, __int_as_float(m1.y), acc);
        acc = fmaf(v3, __int_as_float(m1.w), acc);
        acc = fmaf(v4, __int_as_float(m2.y), acc);
        acc = fmaf(v5, __int_as_float(m2.w), acc);
        acc = fmaf(v6, __int_as_float(m3.y), acc);
        acc = fmaf(v7, __int_as_float(m3.w), acc);
    }
    for (; e < e1; ++e) {
        int2 m = epack[e];
        acc = fmaf(hw[(size_t)m.x * HDIM + lane], __int_as_float(m.y), acc);
    }
    if (RELU_OUT) acc = fmaxf(acc, 0.0f);
    h[(size_t)node * HDIM + lane] = acc;
}

// ---------------------------------------------------------------------------
__global__ __launch_bounds__(256) void pool_k(const float* __restrict__ h,
                                              const int* __restrict__ batch,
                                              const float* __restrict__ lw,
                                              float* __restrict__ gsum,
                                              float* __restrict__ gcnt) {
    int i = blockIdx.x * blockDim.x + threadIdx.x;
    bool act = i < N_NODES;
    float dot = 0.0f;
    int g = -1;
    if (act) {
        g = batch[i];
        const float4* row = (const float4*)(h + (size_t)i * HDIM);
        const float4* w4  = (const float4*)lw;
#pragma unroll
        for (int q = 0; q < 16; ++q) {
            float4 v = row[q], w = w4[q];
            dot = fmaf(v.x, w.x, dot);
            dot = fmaf(v.y, w.y, dot);
            dot = fmaf(v.z, w.z, dot);
            dot = fmaf(v.w, w.w, dot);
        }
    }
    int g0 = __shfl(g, 0);
    bool uni = (__ballot(act && (g == g0)) == ~0ULL);
    if (uni) {
        for (int o = 32; o > 0; o >>= 1) dot += __shfl_down(dot, o);
        if ((threadIdx.x & 63) == 0) {
            atomicAdd(&gsum[g0], dot);
            atomicAdd(&gcnt[g0], 64.0f);
        }
    } else if (act) {
        atomicAdd(&gsum[g], dot);
        atomicAdd(&gcnt[g], 1.0f);
    }
}

__global__ void final_k(float* __restrict__ out, const float* __restrict__ gsum,
                        const float* __restrict__ gcnt, const float* __restrict__ lb) {
    int g = blockIdx.x * blockDim.x + threadIdx.x;
    if (g < N_GRAPHS) out[g] = gsum[g] / fmaxf(gcnt[g], 1.0f) + lb[0];
}

// ---------------------------------------------------------------------------
extern "C" void kernel_launch(void* const* d_in, const int* in_sizes, int n_in,
                              void* d_out, int out_size, void* d_ws, size_t ws_size,
                              hipStream_t stream) {
    const float* x     = (const float*)d_in[0];
    const int*   eidx  = (const int*)d_in[1];   // [2, E] int32
    const int*   batch = (const int*)d_in[3];
    const float* W1 = (const float*)d_in[4];
    const float* b1 = (const float*)d_in[5];
    const float* W2 = (const float*)d_in[6];
    const float* b2 = (const float*)d_in[7];
    const float* W3 = (const float*)d_in[8];
    const float* b3 = (const float*)d_in[9];
    const float* lin_w = (const float*)d_in[10];
    const float* lin_b = (const float*)d_in[11];
    float* out = (float*)d_out;

    const int* src = eidx;
    const int* dst = eidx + N_EDGES;

    float* ws     = (float*)d_ws;
    float* dinv   = ws;                         // 100352
    int*   cnt    = (int*)(ws + 100352);        // 100352
    int*   rowptr = cnt + 100352;               // 100352 (needs 100001)
    int*   cursor = rowptr + 100352;            // 100352
    int*   bsum   = cursor + 100352;            // 512
    int*   boff   = bsum + 512;                 // 512
    int2*  epack  = (int2*)(boff + 512);        // 1.6M int2 (12.8 MB), 16B-aligned
    float* bufA   = (float*)(epack + N_EDGES);  // 6.4M
    float* bufB   = bufA + 6400000;             // 6.4M
    float* gsum   = bufB + 6400000;             // 1024
    float* gcnt   = gsum + 1024;                // 1024   (~65 MB total)

    // ---- CSR build (once; reused by all 3 layers) ----
    zero_k<<<512, 256, 0, stream>>>(cnt, gsum, gcnt);
    hist_k<<<4096, 256, 0, stream>>>(dst, cnt);
    dinv_k<<<(N_NODES + 255) / 256, 256, 0, stream>>>(cnt, dinv);
    scan_block_k<<<NB_SCAN, 256, 0, stream>>>(cnt, bsum);
    scan_top_k<<<1, 512, 0, stream>>>(bsum, boff);
    scan_write_k<<<NB_SCAN, 256, 0, stream>>>(cnt, boff, rowptr, cursor);
    bucket_k<<<4096, 256, 0, stream>>>(src, dst, dinv, cursor, epack);

    // ---- 3 GCN layers (relu folded into agg store) ----
    gemm_k<F_IN><<<782, 256, 0, stream>>>(x, W1, bufA);
    agg_k<true><<<25000, 256, 0, stream>>>(rowptr, epack, dinv, bufA, b1, bufB);

    gemm_k<HDIM><<<782, 256, 0, stream>>>(bufB, W2, bufA);
    agg_k<true><<<25000, 256, 0, stream>>>(rowptr, epack, dinv, bufA, b2, bufB);

    gemm_k<HDIM><<<782, 256, 0, stream>>>(bufB, W3, bufA);
    agg_k<false><<<25000, 256, 0, stream>>>(rowptr, epack, dinv, bufA, b3, bufB);

    // ---- pool + head ----
    pool_k<<<(N_NODES + 255) / 256, 256, 0, stream>>>(bufB, batch, lin_w, gsum, gcnt);
    final_k<<<(N_GRAPHS + 255) / 256, 256, 0, stream>>>(out, gsum, gcnt, lin_b);
}